// Round 1
// baseline (15818.539 us; speedup 1.0000x reference)
//
#include <hip/hip_runtime.h>

#define NROWS 65536
#define DD 512
#define MSZ (DD * DD)          // 262144 floats = 1 MB
#define NS_ITERS 7
#define BARY_ITERS 16
#define KSPLIT 8
#define KCHUNK (NROWS / KSPLIT)  // 8192

// ---------------- column means ----------------
__global__ __launch_bounds__(512) void colsum_kernel(const float* __restrict__ X,
                                                     const float* __restrict__ S,
                                                     float* __restrict__ sums) {
    const float* src = (blockIdx.y == 0) ? X : S;
    float* dst = sums + blockIdx.y * DD;
    int col = threadIdx.x;
    long base = (long)blockIdx.x * 256 * DD;
    float acc = 0.f;
    #pragma unroll 8
    for (int r = 0; r < 256; ++r)
        acc += src[base + (long)r * DD + col];
    atomicAdd(dst + col, acc);
}

__global__ __launch_bounds__(512) void finalize_mean_kernel(float* __restrict__ ws) {
    int t = threadIdx.x;
    const float inv_n = 1.f / (float)NROWS;
    float mc = ws[t] * inv_n;
    float ms = ws[DD + t] * inv_n;
    ws[t] = mc;
    ws[DD + t] = ms;
    ws[2 * DD + t] = 0.5f * (mc + ms);   // mu_bary
}

// ---------------- covariance: G = X^T X (split-K, upper tiles only) ----------------
__global__ __launch_bounds__(256) void covsyrk_kernel(const float* __restrict__ X,
                                                      const float* __restrict__ S,
                                                      float* __restrict__ G) {
    if (blockIdx.x > blockIdx.y) return;   // symmetry: only tiles a0 <= b0
    __shared__ float As[16][68];
    __shared__ float Bs[16][68];
    int mat = blockIdx.z / KSPLIT;
    int ks  = blockIdx.z % KSPLIT;
    const float* src = (mat == 0) ? X : S;
    float* g = G + (long)mat * MSZ;
    int a0 = blockIdx.x * 64, b0 = blockIdx.y * 64;
    int t = threadIdx.x;
    int rr = t >> 4;              // 0..15 (k row within chunk)
    int c4 = (t & 15) << 2;       // 0..60
    int tx = t & 15, ty = t >> 4;
    float acc[4][4] = {};
    long r0 = (long)ks * KCHUNK;
    for (int k0 = 0; k0 < KCHUNK; k0 += 16) {
        long base = (r0 + k0 + rr) * DD;
        float4 av = *(const float4*)(src + base + a0 + c4);
        float4 bv = *(const float4*)(src + base + b0 + c4);
        *(float4*)&As[rr][c4] = av;
        *(float4*)&Bs[rr][c4] = bv;
        __syncthreads();
        #pragma unroll
        for (int kk = 0; kk < 16; ++kk) {
            float4 a = *(const float4*)&As[kk][ty << 2];
            float4 b = *(const float4*)&Bs[kk][tx << 2];
            float af[4] = {a.x, a.y, a.z, a.w};
            float bf[4] = {b.x, b.y, b.z, b.w};
            #pragma unroll
            for (int i = 0; i < 4; ++i)
                #pragma unroll
                for (int j = 0; j < 4; ++j)
                    acc[i][j] += af[i] * bf[j];
        }
        __syncthreads();
    }
    #pragma unroll
    for (int i = 0; i < 4; ++i)
        #pragma unroll
        for (int j = 0; j < 4; ++j)
            atomicAdd(&g[(long)(a0 + ty * 4 + i) * DD + b0 + tx * 4 + j], acc[i][j]);
}

// cov = (G - n m m^T) / (n-1); reads upper tile (mirror), writes full matrix (no race: separate out buf)
__global__ __launch_bounds__(512) void covfix_kernel(const float* __restrict__ Gt,
                                                     float* __restrict__ C,
                                                     const float* __restrict__ means) {
    int m = blockIdx.y, i = blockIdx.x, j = threadIdx.x;
    const float* mu = means + m * DD;
    const float* g = Gt + (long)m * MSZ;
    int ii = i, jj = j;
    if ((ii >> 6) > (jj >> 6)) { int tmp = ii; ii = jj; jj = tmp; }
    float v = g[(long)ii * DD + jj];
    C[(long)m * MSZ + (long)i * DD + j] =
        (v - (float)NROWS * mu[i] * mu[j]) * (1.f / (float)(NROWS - 1));
}

// ---------------- Newton-Schulz support ----------------
// slots per context: [c, 1/c, sqrt(c), 1/sqrt(c)]
__global__ __launch_bounds__(512) void trace_kernel(const float* __restrict__ Abase, long long stride,
                                                    float* __restrict__ slotbase, long long slotstride) {
    __shared__ float red[512];
    const float* A = Abase + (long long)blockIdx.x * stride;
    int t = threadIdx.x;
    red[t] = A[(long)t * DD + t];
    __syncthreads();
    for (int s = 256; s > 0; s >>= 1) {
        if (t < s) red[t] += red[t + s];
        __syncthreads();
    }
    if (t == 0) {
        float c = 2.5f * red[0] / (float)DD;   // c > lambda_max with big margin (spectra ~ I)
        float* sl = slotbase + (long long)blockIdx.x * slotstride;
        sl[0] = c;
        sl[1] = 1.f / c;
        sl[2] = sqrtf(c);
        sl[3] = 1.f / sqrtf(c);
    }
}

__global__ __launch_bounds__(512) void nsinit_kernel(const float* __restrict__ Abase, long long sA,
                                                     float* __restrict__ Ybase, long long sY,
                                                     float* __restrict__ Zbase, long long sZ,
                                                     const float* __restrict__ slotbase, long long slotstride) {
    int z = blockIdx.y;
    const float* A = Abase + (long long)z * sA;
    float* Y = Ybase + (long long)z * sY;
    float* Z = Zbase + (long long)z * sZ;
    float invc = slotbase[(long long)z * slotstride + 1];
    int idx = blockIdx.x * 512 + threadIdx.x;
    int row = idx >> 9, col = idx & 511;
    Y[idx] = A[idx] * invc;
    Z[idx] = (row == col) ? 1.f : 0.f;
}

// ---------------- generic 512x512 batched matmul: C_z = alpha_eff*(A_z@B_z) + beta*D_z ----------------
__global__ __launch_bounds__(256) void mm512_kernel(const float* __restrict__ Ab, long long sA,
                                                    const float* __restrict__ Bb, long long sB,
                                                    const float* __restrict__ Db, long long sD,
                                                    float* __restrict__ Cb, long long sC,
                                                    float alpha, float beta,
                                                    const float* __restrict__ alphaPtr) {
    __shared__ float As[32][36];
    __shared__ float Bs[32][36];
    long long z = blockIdx.z;
    const float* A = Ab + z * sA;
    const float* B = Bb + z * sB;
    const float* Dm = Db + z * sD;
    float* C = Cb + z * sC;
    int i0 = blockIdx.y * 32, j0 = blockIdx.x * 32;
    int t = threadIdx.x;
    int lr = t >> 3;              // 0..31
    int lc4 = (t & 7) << 2;       // 0..28
    int tx = t & 15, ty = t >> 4;
    float acc[2][2] = {};
    for (int k0 = 0; k0 < DD; k0 += 32) {
        float4 av = *(const float4*)(A + (long)(i0 + lr) * DD + k0 + lc4);
        float4 bv = *(const float4*)(B + (long)(k0 + lr) * DD + j0 + lc4);
        As[lc4 + 0][lr] = av.x; As[lc4 + 1][lr] = av.y;
        As[lc4 + 2][lr] = av.z; As[lc4 + 3][lr] = av.w;
        *(float4*)&Bs[lr][lc4] = bv;
        __syncthreads();
        #pragma unroll
        for (int kk = 0; kk < 32; ++kk) {
            float2 a = *(const float2*)&As[kk][ty << 1];
            float2 b = *(const float2*)&Bs[kk][tx << 1];
            acc[0][0] += a.x * b.x; acc[0][1] += a.x * b.y;
            acc[1][0] += a.y * b.x; acc[1][1] += a.y * b.y;
        }
        __syncthreads();
    }
    float aeff = alpha * (alphaPtr ? *alphaPtr : 1.f);
    #pragma unroll
    for (int i = 0; i < 2; ++i)
        #pragma unroll
        for (int j = 0; j < 2; ++j) {
            long idx = (long)(i0 + (ty << 1) + i) * DD + j0 + (tx << 1) + j;
            float v = aeff * acc[i][j];
            if (beta != 0.f) v += beta * Dm[idx];
            C[idx] = v;
        }
}

// Q = 0.5*(sqrt(c0)*Y0 + sqrt(c1)*Y1)
__global__ __launch_bounds__(512) void combineQ_kernel(const float* __restrict__ Y0,
                                                       const float* __restrict__ Y1,
                                                       const float* __restrict__ sl1,
                                                       const float* __restrict__ sl2,
                                                       float* __restrict__ Q) {
    int idx = blockIdx.x * 512 + threadIdx.x;
    Q[idx] = 0.5f * (sl1[2] * Y0[idx] + sl2[2] * Y1[idx]);
}

__global__ __launch_bounds__(512) void symmetrize_kernel(const float* __restrict__ V,
                                                         float* __restrict__ Sg) {
    int i = blockIdx.x, j = threadIdx.x;
    Sg[(long)i * DD + j] = 0.5f * (V[(long)i * DD + j] + V[(long)j * DD + i]);
}

// bias_j = mu_b[j] - sum_k mu_c[k]*M[j][k]
__global__ __launch_bounds__(64) void bias_kernel(const float* __restrict__ M,
                                                  const float* __restrict__ means,
                                                  float* __restrict__ bias) {
    int j = blockIdx.x;
    int lane = threadIdx.x;
    const float* mu_c = means;
    const float* mu_b = means + 2 * DD;
    float p = 0.f;
    for (int k = lane; k < DD; k += 64)
        p += mu_c[k] * M[(long)j * DD + k];
    #pragma unroll
    for (int off = 32; off > 0; off >>= 1)
        p += __shfl_down(p, off, 64);
    if (lane == 0) bias[j] = mu_b[j] - p;
}

// out = X @ M^T + bias  (row-broadcast bias)
__global__ __launch_bounds__(256) void outgemm_kernel(const float* __restrict__ X,
                                                      const float* __restrict__ M,
                                                      const float* __restrict__ bias,
                                                      float* __restrict__ out) {
    __shared__ float As[16][68];
    __shared__ float Bs[16][68];
    int j0 = blockIdx.x * 64;     // 0..7  -> cols
    int i0 = blockIdx.y * 64;     // 0..1023 -> rows
    int t = threadIdx.x;
    int lr = t >> 2;              // 0..63
    int lc4 = (t & 3) << 2;       // 0,4,8,12
    int tx = t & 15, ty = t >> 4;
    float acc[4][4] = {};
    for (int k0 = 0; k0 < DD; k0 += 16) {
        float4 xa = *(const float4*)(X + (long)(i0 + lr) * DD + k0 + lc4);
        float4 mb = *(const float4*)(M + (long)(j0 + lr) * DD + k0 + lc4);
        As[lc4 + 0][lr] = xa.x; As[lc4 + 1][lr] = xa.y;
        As[lc4 + 2][lr] = xa.z; As[lc4 + 3][lr] = xa.w;
        Bs[lc4 + 0][lr] = mb.x; Bs[lc4 + 1][lr] = mb.y;
        Bs[lc4 + 2][lr] = mb.z; Bs[lc4 + 3][lr] = mb.w;
        __syncthreads();
        #pragma unroll
        for (int kk = 0; kk < 16; ++kk) {
            float4 a = *(const float4*)&As[kk][ty << 2];
            float4 b = *(const float4*)&Bs[kk][tx << 2];
            float af[4] = {a.x, a.y, a.z, a.w};
            float bf[4] = {b.x, b.y, b.z, b.w};
            #pragma unroll
            for (int i = 0; i < 4; ++i)
                #pragma unroll
                for (int j = 0; j < 4; ++j)
                    acc[i][j] += af[i] * bf[j];
        }
        __syncthreads();
    }
    #pragma unroll
    for (int i = 0; i < 4; ++i)
        #pragma unroll
        for (int j = 0; j < 4; ++j)
            out[(long)(i0 + ty * 4 + i) * DD + j0 + tx * 4 + j] =
                acc[i][j] + bias[j0 + tx * 4 + j];
}

// ---------------- host orchestration ----------------
extern "C" void kernel_launch(void* const* d_in, const int* in_sizes, int n_in,
                              void* d_out, int out_size, void* d_ws, size_t ws_size,
                              hipStream_t stream) {
    const float* X = (const float*)d_in[0];
    const float* S = (const float*)d_in[1];
    float* out = (float*)d_out;
    float* ws = (float*)d_ws;

    // ws layout (floats):
    // [0,512)=mean_c  [512,1024)=mean_s  [1024,1536)=mu_b  [1536,2048)=bias
    // [2048..)=scalar slots (ctx0@2048, ctx1@2056, ctx2@2064)
    // 4096 + idx*MSZ = matrices (24 of them)
    float* bias  = ws + 1536;
    float* slot0 = ws + 2048;
    float* slot1 = ws + 2056;
    float* MATS  = ws + 4096;
    auto m = [&](int i) { return MATS + (long long)i * MSZ; };
    // 0 covc, 1 covs, 2 Sigma, 3 Y, 4 Z, 5 Yn, 6 Zn, 7 W/U, 8 P0/V/M, 9 P1/Q,
    // 10-11 Yb, 12-13 Wb, 14-15 Zb, 16-17 Ybn, 18-19 Zbn, 20-21 mid, 22-23 Gtmp
    float* covc  = m(0);
    float* Sigma = m(2);
    float* Gtmp  = m(22);

    hipMemsetAsync(ws, 0, 1024 * sizeof(float), stream);             // mean sums
    hipMemsetAsync(Gtmp, 0, 2ll * MSZ * sizeof(float), stream);      // syrk accumulators

    colsum_kernel<<<dim3(256, 2), 512, 0, stream>>>(X, S, ws);
    finalize_mean_kernel<<<1, 512, 0, stream>>>(ws);
    covsyrk_kernel<<<dim3(8, 8, 2 * KSPLIT), 256, 0, stream>>>(X, S, Gtmp);
    covfix_kernel<<<dim3(512, 2), 512, 0, stream>>>(Gtmp, covc, ws);
    hipMemcpyAsync(Sigma, covc, MSZ * sizeof(float), hipMemcpyDeviceToDevice, stream);

    auto mm = [&](const float* A, long long sA, const float* B, long long sB,
                  const float* Dm, long long sD, float* C, long long sC,
                  float alpha, float beta, const float* aptr, int batch) {
        mm512_kernel<<<dim3(16, 16, batch), 256, 0, stream>>>(A, sA, B, sB, Dm, sD, C, sC,
                                                              alpha, beta, aptr);
    };

    // coupled Newton-Schulz, single matrix, buffers m(3..7); returns final Y,Z ptrs
    auto ns_single = [&](const float* Ain, float* slots, float*& Yout, float*& Zout) {
        trace_kernel<<<1, 512, 0, stream>>>(Ain, 0, slots, 0);
        nsinit_kernel<<<dim3(512, 1), 512, 0, stream>>>(Ain, 0, m(3), 0, m(4), 0, slots, 0);
        float *Y = m(3), *Z = m(4), *Yn = m(5), *Zn = m(6), *W = m(7);
        for (int it = 0; it < NS_ITERS; ++it) {
            mm(Z, 0, Y, 0, W, 0, W, 0, 1.f, 0.f, nullptr, 1);                 // W = Z@Y
            // z=0: Yn = 1.5Y - 0.5*Y@W ; z=1: Zn = 1.5Z - 0.5*W@Z  (base+stride batching)
            mm(Y, W - Y, W, Z - W, Y, Z - Y, Yn, Zn - Yn, -0.5f, 1.5f, nullptr, 2);
            float* tp = Y; Y = Yn; Yn = tp;
            tp = Z; Z = Zn; Zn = tp;
        }
        Yout = Y; Zout = Z;
    };

    // batched (nb=1 or 2) NS on contiguous matrices at Abase; returns final Y base ptr
    auto ns_batch = [&](const float* Abase, int nb, float* slots, float*& Yout) {
        trace_kernel<<<nb, 512, 0, stream>>>(Abase, MSZ, slots, 8);
        nsinit_kernel<<<dim3(512, nb), 512, 0, stream>>>(Abase, MSZ, m(10), MSZ, m(14), MSZ, slots, 8);
        float *Y = m(10), *Z = m(14), *Yn = m(16), *Zn = m(18), *W = m(12);
        for (int it = 0; it < NS_ITERS; ++it) {
            mm(Z, MSZ, Y, MSZ, W, MSZ, W, MSZ, 1.f, 0.f, nullptr, nb);        // W = Z@Y
            mm(Y, MSZ, W, MSZ, Y, MSZ, Yn, MSZ, -0.5f, 1.5f, nullptr, nb);    // Yn
            mm(W, MSZ, Z, MSZ, Z, MSZ, Zn, MSZ, -0.5f, 1.5f, nullptr, nb);    // Zn
            float* tp = Y; Y = Yn; Yn = tp;
            tp = Z; Z = Zn; Zn = tp;
        }
        Yout = Y;
    };

    float *Ysig, *Zsig, *Ybc;
    for (int iter = 0; iter < BARY_ITERS; ++iter) {
        ns_single(Sigma, slot0, Ysig, Zsig);         // sqrt(Sigma)=sqrt(c)*Y, inv=Z/sqrt(c)
        // P_j = Y @ cov_j  (batch 2: cov_c, cov_s contiguous; P0,P1 contiguous)
        mm(Ysig, 0, covc, MSZ, m(8), MSZ, m(8), MSZ, 1.f, 0.f, nullptr, 2);
        // mid_j = c0 * P_j @ Y   (= S_sqrt cov_j S_sqrt)
        mm(m(8), MSZ, Ysig, 0, m(20), MSZ, m(20), MSZ, 1.f, 0.f, slot0, 2);
        ns_batch(m(20), 2, slot1, Ybc);
        // Q = 0.5*(sqrt(c1)*Yb0 + sqrt(c2)*Yb1)   (= lam-weighted sqrt(mid) sum)
        combineQ_kernel<<<512, 512, 0, stream>>>(Ybc, Ybc + MSZ, slot1, slot1 + 8, m(9));
        mm(Zsig, 0, m(9), 0, m(7), 0, m(7), 0, 1.f, 0.f, nullptr, 1);         // U = Z@Q
        mm(m(7), 0, Zsig, 0, m(8), 0, m(8), 0, 1.f, 0.f, slot0 + 1, 1);       // V = (1/c0)*U@Z
        symmetrize_kernel<<<512, 512, 0, stream>>>(m(8), Sigma);
    }

    // final transform: M = covc^{-1/2} (covc^{1/2} Sigma covc^{1/2})^{1/2} covc^{-1/2}
    ns_single(covc, slot0, Ysig, Zsig);
    mm(Ysig, 0, Sigma, 0, m(8), 0, m(8), 0, 1.f, 0.f, nullptr, 1);            // P = Y@Sigma
    mm(m(8), 0, Ysig, 0, m(20), 0, m(20), 0, 1.f, 0.f, slot0, 1);             // mid = c0*P@Y
    ns_batch(m(20), 1, slot1, Ybc);
    mm(Zsig, 0, Ybc, 0, m(7), 0, m(7), 0, 1.f, 0.f, slot1 + 2, 1);            // U = sqrt(c1)*Z@Yb
    mm(m(7), 0, Zsig, 0, m(8), 0, m(8), 0, 1.f, 0.f, slot0 + 1, 1);           // M = (1/c0)*U@Z
    bias_kernel<<<512, 64, 0, stream>>>(m(8), ws, bias);
    outgemm_kernel<<<dim3(8, 1024), 256, 0, stream>>>(X, m(8), bias, out);
}